// Round 4
// baseline (2129.756 us; speedup 1.0000x reference)
//
#include <hip/hip_runtime.h>
#include <hip/hip_bf16.h>
#include <cstddef>

// ---------------------------------------------------------------------------
// 2-layer GCN: out = A_norm(relu(A_norm(x@W1)+b1) @ W2) + b2
// R4: CSR replaced by 64-node bucket staging (4B packed edges, write-head
// locality); aggregation = block-per-bucket LDS fp32 accumulate (ds_add_f32).
// GEMM1: M-tile 64, register-prefetch pipelined MFMA. h/h1/h2 bf16,
// pre-scaled by dinv in GEMM epilogues.
// ---------------------------------------------------------------------------

#define IN_F 512
#define HID 128
#define NCLS 32

typedef __attribute__((ext_vector_type(8))) short bf16x8;
typedef __attribute__((ext_vector_type(4))) float f32x4;

__device__ __forceinline__ unsigned short f2bf(float f) {
    union { float f; unsigned u; } v; v.f = f;
    unsigned r = v.u + 0x7fff + ((v.u >> 16) & 1);   // RNE
    return (unsigned short)(r >> 16);
}
__device__ __forceinline__ float bf2f(unsigned short h) {
    union { unsigned u; float f; } v; v.u = ((unsigned)h) << 16;
    return v.f;
}
__device__ __forceinline__ float lo16(unsigned u) { return bf2f((unsigned short)(u & 0xffff)); }
__device__ __forceinline__ float hi16(unsigned u) { return bf2f((unsigned short)(u >> 16)); }

// ---------------- degree histogram ----------------
__global__ void k_hist(const int* __restrict__ dst, int* __restrict__ deg, int E) {
    int e = blockIdx.x * 256 + threadIdx.x;
    if (e < E) atomicAdd(&deg[dst[e]], 1);
}

// ---------------- dinv + per-bucket counts (bucket = 64 nodes = 1 wave span) ----------------
__global__ __launch_bounds__(256) void k_dinv(const int* __restrict__ deg, float* __restrict__ dinv,
                                              int* __restrict__ bcnt, int n) {
    int i = blockIdx.x * 256 + threadIdx.x;
    int d = (i < n) ? deg[i] : 0;
    if (i < n) dinv[i] = rsqrtf((float)d + 1.0f);
    int s = d;
#pragma unroll
    for (int off = 1; off < 64; off <<= 1) s += __shfl_xor(s, off, 64);
    if ((threadIdx.x & 63) == 0 && i < n) bcnt[i >> 6] = s;
}

// ---------------- W1 [512][128] fp32 -> W1T [128][512] bf16 bits ----------------
__global__ void k_prep(const float* __restrict__ W1, unsigned short* __restrict__ W1T) {
    int i = blockIdx.x * 256 + threadIdx.x;
    int n = i >> 9, k = i & 511;
    W1T[(size_t)n * IN_F + k] = f2bf(W1[(size_t)k * HID + n]);
}

// ---------------- single-block exclusive scan over nb (<=2048) buckets ----------------
__global__ __launch_bounds__(256) void k_bscan(const int* __restrict__ bcnt, int* __restrict__ boff,
                                               int* __restrict__ bcur, int nb) {
    __shared__ int sd[256];
    int base = threadIdx.x * 8;
    int v[8];
    int t = 0;
#pragma unroll
    for (int j = 0; j < 8; ++j) {
        int x = (base + j < nb) ? bcnt[base + j] : 0;
        v[j] = t;
        t += x;
    }
    sd[threadIdx.x] = t;
    __syncthreads();
    for (int off = 1; off < 256; off <<= 1) {
        int x = 0;
        if ((int)threadIdx.x >= off) x = sd[threadIdx.x - off];
        __syncthreads();
        if ((int)threadIdx.x >= off) sd[threadIdx.x] += x;
        __syncthreads();
    }
    int excl = sd[threadIdx.x] - t;
#pragma unroll
    for (int j = 0; j < 8; ++j) {
        if (base + j < nb) {
            int o = excl + v[j];
            boff[base + j] = o;
            bcur[base + j] = o;
        }
    }
    if (threadIdx.x == 255) boff[nb] = sd[255];
}

// ---------------- bucket scatter: stage[pos] = src<<6 | dst&63 ----------------
__global__ void k_bscatter(const int* __restrict__ src, const int* __restrict__ dst,
                           int* bcur, unsigned* __restrict__ stage, int E) {
    int e = blockIdx.x * 256 + threadIdx.x;
    if (e < E) {
        int s = src[e];
        int d = dst[e];
        int pos = atomicAdd(&bcur[d >> 6], 1);
        stage[pos] = ((unsigned)s << 6) | (unsigned)(d & 63);
    }
}

// ---------------- GEMM1: x[M,512]fp32 @ W1T[128,512]bf16 -> hs[M,128]bf16 (dinv-scaled) ----
// M-tile 64, 4 waves x 16 rows, register-prefetch pipeline.
#define LSTR 40
__global__ __launch_bounds__(256) void k_gemm1(const float* __restrict__ A,
                                               const unsigned short* __restrict__ BT,
                                               const float* __restrict__ dinv,
                                               unsigned short* __restrict__ C, int M) {
    __shared__ unsigned short As[64 * LSTR];
    __shared__ unsigned short Bs[128 * LSTR];
    const int tid = threadIdx.x;
    const int wave = tid >> 6;
    const int lane = tid & 63;
    const int l16 = lane & 15;
    const int q = lane >> 4;
    const int rowBase = blockIdx.x * 64;

    // A staging: thread -> row r = tid>>2, k-chunk kc = tid&3 (8 k-vals = 2 float4)
    const int ar = tid >> 2, akc = tid & 3;
    const int agr = rowBase + ar;
    // B staging: two chunks: c = tid, tid+256; n = c>>2, kc = c&3
    const int bn0 = tid >> 2, bn1 = 64 + (tid >> 2), bkc = tid & 3;

    f32x4 acc[8];
#pragma unroll
    for (int nt = 0; nt < 8; ++nt) acc[nt] = (f32x4){0.f, 0.f, 0.f, 0.f};

    float4 pa0, pa1;
    uint4 pb0, pb1;
    auto load_tile = [&](int k0, float4& a0, float4& a1, uint4& b0, uint4& b1) {
        if (agr < M) {
            const float* ap = A + (size_t)agr * IN_F + k0 + akc * 8;
            a0 = *(const float4*)ap;
            a1 = *(const float4*)(ap + 4);
        } else {
            a0 = make_float4(0.f, 0.f, 0.f, 0.f);
            a1 = a0;
        }
        b0 = *(const uint4*)(BT + (size_t)bn0 * IN_F + k0 + bkc * 8);
        b1 = *(const uint4*)(BT + (size_t)bn1 * IN_F + k0 + bkc * 8);
    };

    load_tile(0, pa0, pa1, pb0, pb1);

    for (int t = 0; t < 16; ++t) {
        // pack A fp32->bf16, b128 LDS writes
        ushort4 lohalf, hihalf;
        lohalf.x = f2bf(pa0.x); lohalf.y = f2bf(pa0.y); lohalf.z = f2bf(pa0.z); lohalf.w = f2bf(pa0.w);
        hihalf.x = f2bf(pa1.x); hihalf.y = f2bf(pa1.y); hihalf.z = f2bf(pa1.z); hihalf.w = f2bf(pa1.w);
        *(ushort4*)(As + ar * LSTR + akc * 8) = lohalf;
        *(ushort4*)(As + ar * LSTR + akc * 8 + 4) = hihalf;
        *(uint4*)(Bs + bn0 * LSTR + bkc * 8) = pb0;
        *(uint4*)(Bs + bn1 * LSTR + bkc * 8) = pb1;
        __syncthreads();

        float4 na0, na1;
        uint4 nb0, nb1;
        if (t < 15) load_tile((t + 1) * 32, na0, na1, nb0, nb1);

        bf16x8 a_frag = *(const bf16x8*)(As + (wave * 16 + l16) * LSTR + q * 8);
        bf16x8 b_frag[8];
#pragma unroll
        for (int nt = 0; nt < 8; ++nt)
            b_frag[nt] = *(const bf16x8*)(Bs + (nt * 16 + l16) * LSTR + q * 8);
#pragma unroll
        for (int nt = 0; nt < 8; ++nt)
            acc[nt] = __builtin_amdgcn_mfma_f32_16x16x32_bf16(a_frag, b_frag[nt], acc[nt], 0, 0, 0);
        __syncthreads();
        pa0 = na0; pa1 = na1; pb0 = nb0; pb1 = nb1;
    }

    // epilogue: C/D col=l16, row=q*4+r; fuse dinv scale
#pragma unroll
    for (int r = 0; r < 4; ++r) {
        int row = rowBase + wave * 16 + q * 4 + r;
        if (row < M) {
            float sc = dinv[row];
#pragma unroll
            for (int nt = 0; nt < 8; ++nt)
                C[(size_t)row * HID + nt * 16 + l16] = f2bf(acc[nt][r] * sc);
        }
    }
}

// ---------------- agg1: block per bucket, LDS fp32 accumulate, 4 edges/wave in flight ----------------
__global__ __launch_bounds__(256) void k_agg1(const unsigned short* __restrict__ hs,
                                              const unsigned* __restrict__ stage,
                                              const int* __restrict__ boff,
                                              const float* __restrict__ dinv, const float* __restrict__ b1,
                                              unsigned short* __restrict__ h1, int N) {
    __shared__ float acc[64 * HID];   // 32 KB
    const int tid = threadIdx.x;
    const int b = blockIdx.x;
#pragma unroll
    for (int it = 0; it < 32; ++it) acc[tid + 256 * it] = 0.f;
    __syncthreads();

    const int wave = tid >> 6;
    const int lane = tid & 63;
    const int e0 = boff[b], e1 = boff[b + 1];
    const unsigned* hu = (const unsigned*)hs;

    for (int e = e0 + wave * 4; e < e1; e += 16) {
        int n = e1 - e; if (n > 4) n = 4;
        unsigned u[4]; int dl[4];
        for (int j = 0; j < n; ++j) {
            unsigned w = stage[e + j];
            dl[j] = (int)(w & 63u);
            u[j] = hu[(size_t)(w >> 6) * 64 + lane];
        }
        for (int j = 0; j < n; ++j) {
            atomicAdd(&acc[dl[j] * HID + 2 * lane], lo16(u[j]));
            atomicAdd(&acc[dl[j] * HID + 2 * lane + 1], hi16(u[j]));
        }
    }
    __syncthreads();

    float2 bb = ((const float2*)b1)[lane];
#pragma unroll
    for (int k = 0; k < 16; ++k) {
        int nlo = wave * 16 + k;
        int v = b * 64 + nlo;
        if (v < N) {
            float dv = dinv[v];
            unsigned su = hu[(size_t)v * 64 + lane];
            float ax = acc[nlo * HID + 2 * lane] + lo16(su);
            float ay = acc[nlo * HID + 2 * lane + 1] + hi16(su);
            float ox = fmaxf(dv * ax + bb.x, 0.f);
            float oy = fmaxf(dv * ay + bb.y, 0.f);
            ((unsigned*)h1)[(size_t)v * 64 + lane] =
                (unsigned)f2bf(ox) | ((unsigned)f2bf(oy) << 16);
        }
    }
}

// ---------------- GEMM2: h1[M,128]bf16 @ W2[128,32]fp32 -> h2s[M,32]bf16 (dinv-scaled) ----------------
__global__ __launch_bounds__(256) void k_gemm2(const unsigned short* __restrict__ A,
                                               const float* __restrict__ B,
                                               const float* __restrict__ dinv,
                                               unsigned short* __restrict__ C, int M) {
    __shared__ float Bs[HID][NCLS];
    __shared__ float As[64][HID];
    const int tid = threadIdx.x;
#pragma unroll
    for (int it = 0; it < 16; ++it) {
        int idx = tid + 256 * it;
        Bs[idx >> 5][idx & 31] = B[idx];
    }
    int rowBase = blockIdx.x * 64;
    const unsigned* A2 = (const unsigned*)A;
#pragma unroll
    for (int it = 0; it < 16; ++it) {
        int idx = tid + 256 * it;
        int r = idx >> 6, c2 = idx & 63;
        int gr = rowBase + r;
        unsigned u = (gr < M) ? A2[(size_t)gr * 64 + c2] : 0u;
        As[r][2 * c2]     = lo16(u);
        As[r][2 * c2 + 1] = hi16(u);
    }
    __syncthreads();
    int col = tid & 31;
    int rg = tid >> 5;
    float acc[8];
#pragma unroll
    for (int i = 0; i < 8; ++i) acc[i] = 0.f;
    for (int k = 0; k < HID; ++k) {
        float b = Bs[k][col];
#pragma unroll
        for (int i = 0; i < 8; ++i) acc[i] += As[rg * 8 + i][k] * b;
    }
#pragma unroll
    for (int i = 0; i < 8; ++i) {
        int gr = rowBase + rg * 8 + i;
        if (gr < M) C[(size_t)gr * NCLS + col] = f2bf(acc[i] * dinv[gr]);
    }
}

// ---------------- agg2: block per bucket, LDS accumulate, quarter-wave per edge ----------------
__global__ __launch_bounds__(256) void k_agg2(const unsigned short* __restrict__ h2s,
                                              const unsigned* __restrict__ stage,
                                              const int* __restrict__ boff,
                                              const float* __restrict__ dinv, const float* __restrict__ b2,
                                              float* __restrict__ out, int N) {
    __shared__ float acc[64 * NCLS];   // 8 KB
    const int tid = threadIdx.x;
    const int b = blockIdx.x;
#pragma unroll
    for (int it = 0; it < 8; ++it) acc[tid + 256 * it] = 0.f;
    __syncthreads();

    const int wave = tid >> 6;
    const int lane = tid & 63;
    const int q = lane >> 4;
    const int l = lane & 15;
    const int e0 = boff[b], e1 = boff[b + 1];
    const unsigned* h2u = (const unsigned*)h2s;

    for (int e = e0 + wave * 8; e < e1; e += 32) {
#pragma unroll
        for (int rep = 0; rep < 2; ++rep) {
            int idx = e + rep * 4 + q;
            if (idx < e1) {
                unsigned w = stage[idx];
                int dlo = (int)(w & 63u);
                unsigned u = h2u[(size_t)(w >> 6) * 16 + l];
                atomicAdd(&acc[dlo * NCLS + 2 * l], lo16(u));
                atomicAdd(&acc[dlo * NCLS + 2 * l + 1], hi16(u));
            }
        }
    }
    __syncthreads();

    // epilogue: thread -> node tid>>2, 8 feats at (tid&3)*8
    int nlo = tid >> 2;
    int fo = (tid & 3) * 8;
    int v = b * 64 + nlo;
    if (v < N) {
        float dv = dinv[v];
        uint4 su = *(const uint4*)(h2u + (size_t)v * 16 + fo / 2);
        float s[8];
        s[0] = lo16(su.x); s[1] = hi16(su.x); s[2] = lo16(su.y); s[3] = hi16(su.y);
        s[4] = lo16(su.z); s[5] = hi16(su.z); s[6] = lo16(su.w); s[7] = hi16(su.w);
        float o[8];
#pragma unroll
        for (int j = 0; j < 8; ++j)
            o[j] = dv * (acc[nlo * NCLS + fo + j] + s[j]) + b2[fo + j];
        float4 o0 = make_float4(o[0], o[1], o[2], o[3]);
        float4 o1 = make_float4(o[4], o[5], o[6], o[7]);
        *(float4*)(out + (size_t)v * NCLS + fo) = o0;
        *(float4*)(out + (size_t)v * NCLS + fo + 4) = o1;
    }
}

// ---------------------------------------------------------------------------
extern "C" void kernel_launch(void* const* d_in, const int* in_sizes, int n_in,
                              void* d_out, int out_size, void* d_ws, size_t ws_size,
                              hipStream_t stream) {
    const float* x = (const float*)d_in[0];
    const int* edge_index = (const int*)d_in[1];
    const float* W1 = (const float*)d_in[2];
    const float* b1 = (const float*)d_in[3];
    const float* W2 = (const float*)d_in[4];
    const float* b2 = (const float*)d_in[5];
    float* out = (float*)d_out;

    const int N = in_sizes[0] / IN_F;       // 100000
    const int E = in_sizes[1] / 2;          // 1600000
    const int NB = (N + 63) >> 6;           // 1563 buckets
    const int* e_src = edge_index;
    const int* e_dst = edge_index + E;

    char* ws = (char*)d_ws;
    size_t off = 0;
    auto alloc = [&](size_t bytes) -> char* {
        char* p = ws + off;
        off += (bytes + 255) & ~(size_t)255;
        return p;
    };
    int* deg             = (int*)alloc((size_t)N * 4);
    float* dinv          = (float*)alloc((size_t)N * 4);
    int* bcnt            = (int*)alloc(4096 * 4);
    int* boff            = (int*)alloc(4096 * 4);
    int* bcur            = (int*)alloc(4096 * 4);
    unsigned* stage      = (unsigned*)alloc((size_t)E * 4);
    unsigned short* W1T  = (unsigned short*)alloc((size_t)HID * IN_F * 2);
    unsigned short* hs   = (unsigned short*)alloc((size_t)N * HID * 2);
    unsigned short* h1   = (unsigned short*)alloc((size_t)N * HID * 2);
    unsigned short* h2s  = (unsigned short*)alloc((size_t)N * NCLS * 2);

    const int nbE = (E + 255) / 256;
    const int nbN = (N + 255) / 256;

    hipMemsetAsync(deg, 0, (size_t)N * 4, stream);
    k_hist<<<nbE, 256, 0, stream>>>(e_dst, deg, E);
    k_dinv<<<nbN, 256, 0, stream>>>(deg, dinv, bcnt, N);
    k_bscan<<<1, 256, 0, stream>>>(bcnt, boff, bcur, NB);
    k_bscatter<<<nbE, 256, 0, stream>>>(e_src, e_dst, bcur, stage, E);
    k_prep<<<(HID * IN_F) / 256, 256, 0, stream>>>(W1, W1T);

    k_gemm1<<<(N + 63) / 64, 256, 0, stream>>>(x, W1T, dinv, hs, N);
    k_agg1<<<NB, 256, 0, stream>>>(hs, stage, boff, dinv, b1, h1, N);
    k_gemm2<<<(N + 63) / 64, 256, 0, stream>>>(h1, W2, dinv, h2s, N);
    k_agg2<<<NB, 256, 0, stream>>>(h2s, stage, boff, dinv, b2, out, N);
}

// Round 5
// 779.376 us; speedup vs baseline: 2.7326x; 2.7326x over previous
//
#include <hip/hip_runtime.h>
#include <hip/hip_bf16.h>
#include <cstddef>

// ---------------------------------------------------------------------------
// 2-layer GCN: out = A_norm(relu(A_norm(x@W1)+b1) @ W2) + b2
// R5: CSR built in two locality-friendly passes (bucket scatter -> per-bucket
// compact with LDS cursors); aggregation = R3's per-node gather (one wave per
// node, unroll x8). GEMM1 = pipelined MFMA, M-tile 64. h/h1/h2 bf16,
// pre-scaled by dinv in GEMM epilogues.
// ---------------------------------------------------------------------------

#define IN_F 512
#define HID 128
#define NCLS 32

typedef __attribute__((ext_vector_type(8))) short bf16x8;
typedef __attribute__((ext_vector_type(4))) float f32x4;

__device__ __forceinline__ unsigned short f2bf(float f) {
    union { float f; unsigned u; } v; v.f = f;
    unsigned r = v.u + 0x7fff + ((v.u >> 16) & 1);   // RNE
    return (unsigned short)(r >> 16);
}
__device__ __forceinline__ float bf2f(unsigned short h) {
    union { unsigned u; float f; } v; v.u = ((unsigned)h) << 16;
    return v.f;
}
__device__ __forceinline__ float lo16(unsigned u) { return bf2f((unsigned short)(u & 0xffff)); }
__device__ __forceinline__ float hi16(unsigned u) { return bf2f((unsigned short)(u >> 16)); }

// ---------------- degree histogram ----------------
__global__ void k_hist(const int* __restrict__ dst, int* __restrict__ deg, int E) {
    int e = blockIdx.x * 256 + threadIdx.x;
    if (e < E) atomicAdd(&deg[dst[e]], 1);
}

// ---------------- dinv + per-bucket counts (bucket = 64 nodes = 1 wave span) ----------------
__global__ __launch_bounds__(256) void k_dinv(const int* __restrict__ deg, float* __restrict__ dinv,
                                              int* __restrict__ bcnt, int n) {
    int i = blockIdx.x * 256 + threadIdx.x;
    int d = (i < n) ? deg[i] : 0;
    if (i < n) dinv[i] = rsqrtf((float)d + 1.0f);
    int s = d;
#pragma unroll
    for (int off = 1; off < 64; off <<= 1) s += __shfl_xor(s, off, 64);
    if ((threadIdx.x & 63) == 0 && i < n) bcnt[i >> 6] = s;
}

// ---------------- W1 [512][128] fp32 -> W1T [128][512] bf16 bits ----------------
__global__ void k_prep(const float* __restrict__ W1, unsigned short* __restrict__ W1T) {
    int i = blockIdx.x * 256 + threadIdx.x;
    int n = i >> 9, k = i & 511;
    W1T[(size_t)n * IN_F + k] = f2bf(W1[(size_t)k * HID + n]);
}

// ---------------- single-block exclusive scan over nb (<=2048) buckets ----------------
__global__ __launch_bounds__(256) void k_bscan(const int* __restrict__ bcnt, int* __restrict__ boff,
                                               int* __restrict__ bcur, int nb) {
    __shared__ int sd[256];
    int base = threadIdx.x * 8;
    int v[8];
    int t = 0;
#pragma unroll
    for (int j = 0; j < 8; ++j) {
        int x = (base + j < nb) ? bcnt[base + j] : 0;
        v[j] = t;
        t += x;
    }
    sd[threadIdx.x] = t;
    __syncthreads();
    for (int off = 1; off < 256; off <<= 1) {
        int x = 0;
        if ((int)threadIdx.x >= off) x = sd[threadIdx.x - off];
        __syncthreads();
        if ((int)threadIdx.x >= off) sd[threadIdx.x] += x;
        __syncthreads();
    }
    int excl = sd[threadIdx.x] - t;
#pragma unroll
    for (int j = 0; j < 8; ++j) {
        if (base + j < nb) {
            int o = excl + v[j];
            boff[base + j] = o;
            bcur[base + j] = o;
        }
    }
    if (threadIdx.x == 255) boff[nb] = sd[255];
}

// ---------------- bucket scatter: stage[pos] = src<<6 | dst&63 ----------------
__global__ void k_bscatter(const int* __restrict__ src, const int* __restrict__ dst,
                           int* bcur, unsigned* __restrict__ stage, int E) {
    int e = blockIdx.x * 256 + threadIdx.x;
    if (e < E) {
        int s = src[e];
        int d = dst[e];
        int pos = atomicAdd(&bcur[d >> 6], 1);
        stage[pos] = ((unsigned)s << 6) | (unsigned)(d & 63);
    }
}

// ---------------- compact: bucket stage -> exact CSR (+ rs) ----------------
// Block per bucket; writes confined to the bucket's contiguous csr span.
__global__ __launch_bounds__(256) void k_compact(const unsigned* __restrict__ stage,
                                                 const int* __restrict__ boff,
                                                 const int* __restrict__ deg,
                                                 int* __restrict__ rs,
                                                 int* __restrict__ csr, int N) {
    __shared__ int cur[64];
    const int b = blockIdx.x;
    const int tid = threadIdx.x;
    const int e0 = boff[b], e1 = boff[b + 1];
    if (tid < 64) {
        int v = b * 64 + tid;
        int d = (v < N) ? deg[v] : 0;
        int x = d;
#pragma unroll
        for (int off = 1; off < 64; off <<= 1) {
            int y = __shfl_up(x, off, 64);
            if (tid >= off) x += y;
        }
        int base = e0 + x - d;   // exclusive prefix within bucket
        if (v < N) rs[v] = base;
        cur[tid] = base;
    }
    __syncthreads();
    for (int e = e0 + tid; e < e1; e += 256) {
        unsigned w = stage[e];
        int pos = atomicAdd(&cur[w & 63u], 1);
        csr[pos] = (int)(w >> 6);
    }
}

// ---------------- GEMM1: x[M,512]fp32 @ W1T[128,512]bf16 -> hs[M,128]bf16 (dinv-scaled) ----
// M-tile 64, 4 waves x 16 rows, register-prefetch pipeline.
#define LSTR 40
__global__ __launch_bounds__(256) void k_gemm1(const float* __restrict__ A,
                                               const unsigned short* __restrict__ BT,
                                               const float* __restrict__ dinv,
                                               unsigned short* __restrict__ C, int M) {
    __shared__ unsigned short As[64 * LSTR];
    __shared__ unsigned short Bs[128 * LSTR];
    const int tid = threadIdx.x;
    const int wave = tid >> 6;
    const int lane = tid & 63;
    const int l16 = lane & 15;
    const int q = lane >> 4;
    const int rowBase = blockIdx.x * 64;

    const int ar = tid >> 2, akc = tid & 3;
    const int agr = rowBase + ar;
    const int bn0 = tid >> 2, bn1 = 64 + (tid >> 2), bkc = tid & 3;

    f32x4 acc[8];
#pragma unroll
    for (int nt = 0; nt < 8; ++nt) acc[nt] = (f32x4){0.f, 0.f, 0.f, 0.f};

    float4 pa0, pa1;
    uint4 pb0, pb1;
    auto load_tile = [&](int k0, float4& a0, float4& a1, uint4& b0, uint4& b1) {
        if (agr < M) {
            const float* ap = A + (size_t)agr * IN_F + k0 + akc * 8;
            a0 = *(const float4*)ap;
            a1 = *(const float4*)(ap + 4);
        } else {
            a0 = make_float4(0.f, 0.f, 0.f, 0.f);
            a1 = a0;
        }
        b0 = *(const uint4*)(BT + (size_t)bn0 * IN_F + k0 + bkc * 8);
        b1 = *(const uint4*)(BT + (size_t)bn1 * IN_F + k0 + bkc * 8);
    };

    load_tile(0, pa0, pa1, pb0, pb1);

    for (int t = 0; t < 16; ++t) {
        ushort4 lohalf, hihalf;
        lohalf.x = f2bf(pa0.x); lohalf.y = f2bf(pa0.y); lohalf.z = f2bf(pa0.z); lohalf.w = f2bf(pa0.w);
        hihalf.x = f2bf(pa1.x); hihalf.y = f2bf(pa1.y); hihalf.z = f2bf(pa1.z); hihalf.w = f2bf(pa1.w);
        *(ushort4*)(As + ar * LSTR + akc * 8) = lohalf;
        *(ushort4*)(As + ar * LSTR + akc * 8 + 4) = hihalf;
        *(uint4*)(Bs + bn0 * LSTR + bkc * 8) = pb0;
        *(uint4*)(Bs + bn1 * LSTR + bkc * 8) = pb1;
        __syncthreads();

        float4 na0, na1;
        uint4 nb0, nb1;
        if (t < 15) load_tile((t + 1) * 32, na0, na1, nb0, nb1);

        bf16x8 a_frag = *(const bf16x8*)(As + (wave * 16 + l16) * LSTR + q * 8);
        bf16x8 b_frag[8];
#pragma unroll
        for (int nt = 0; nt < 8; ++nt)
            b_frag[nt] = *(const bf16x8*)(Bs + (nt * 16 + l16) * LSTR + q * 8);
#pragma unroll
        for (int nt = 0; nt < 8; ++nt)
            acc[nt] = __builtin_amdgcn_mfma_f32_16x16x32_bf16(a_frag, b_frag[nt], acc[nt], 0, 0, 0);
        __syncthreads();
        pa0 = na0; pa1 = na1; pb0 = nb0; pb1 = nb1;
    }

#pragma unroll
    for (int r = 0; r < 4; ++r) {
        int row = rowBase + wave * 16 + q * 4 + r;
        if (row < M) {
            float sc = dinv[row];
#pragma unroll
            for (int nt = 0; nt < 8; ++nt)
                C[(size_t)row * HID + nt * 16 + l16] = f2bf(acc[nt][r] * sc);
        }
    }
}

// ---------------- agg1: one wave per node, unroll x8 (R3 form) ----------------
__global__ __launch_bounds__(256) void k_agg1(const unsigned short* __restrict__ hs,
                                              const int* __restrict__ csr,
                                              const int* __restrict__ rs, const int* __restrict__ cnt,
                                              const float* __restrict__ dinv, const float* __restrict__ b1,
                                              unsigned short* __restrict__ h1, int N) {
    int v = blockIdx.x * 4 + (threadIdx.x >> 6);
    if (v >= N) return;
    int lane = threadIdx.x & 63;
    float dv = dinv[v];
    const unsigned* hrow = (const unsigned*)hs;
    unsigned u = hrow[(size_t)v * 64 + lane];   // self (pre-scaled)
    float ax = lo16(u), ay = hi16(u);
    int start = rs[v];
    int c = cnt[v];
    int i = 0;
    for (; i + 8 <= c; i += 8) {
        int s0 = csr[start + i + 0], s1 = csr[start + i + 1];
        int s2 = csr[start + i + 2], s3 = csr[start + i + 3];
        int s4 = csr[start + i + 4], s5 = csr[start + i + 5];
        int s6 = csr[start + i + 6], s7 = csr[start + i + 7];
        unsigned u0 = hrow[(size_t)s0 * 64 + lane];
        unsigned u1 = hrow[(size_t)s1 * 64 + lane];
        unsigned u2 = hrow[(size_t)s2 * 64 + lane];
        unsigned u3 = hrow[(size_t)s3 * 64 + lane];
        unsigned u4 = hrow[(size_t)s4 * 64 + lane];
        unsigned u5 = hrow[(size_t)s5 * 64 + lane];
        unsigned u6 = hrow[(size_t)s6 * 64 + lane];
        unsigned u7 = hrow[(size_t)s7 * 64 + lane];
        ax += lo16(u0) + lo16(u1) + lo16(u2) + lo16(u3)
            + lo16(u4) + lo16(u5) + lo16(u6) + lo16(u7);
        ay += hi16(u0) + hi16(u1) + hi16(u2) + hi16(u3)
            + hi16(u4) + hi16(u5) + hi16(u6) + hi16(u7);
    }
    for (; i < c; ++i) {
        int s = csr[start + i];
        unsigned us = hrow[(size_t)s * 64 + lane];
        ax += lo16(us);
        ay += hi16(us);
    }
    float2 bb = ((const float2*)b1)[lane];
    float ox = fmaxf(dv * ax + bb.x, 0.f);
    float oy = fmaxf(dv * ay + bb.y, 0.f);
    ((unsigned*)h1)[(size_t)v * 64 + lane] =
        (unsigned)f2bf(ox) | ((unsigned)f2bf(oy) << 16);
}

// ---------------- GEMM2: h1[M,128]bf16 @ W2[128,32]fp32 -> h2s[M,32]bf16 (dinv-scaled) ----------------
__global__ __launch_bounds__(256) void k_gemm2(const unsigned short* __restrict__ A,
                                               const float* __restrict__ B,
                                               const float* __restrict__ dinv,
                                               unsigned short* __restrict__ C, int M) {
    __shared__ float Bs[HID][NCLS];
    __shared__ float As[64][HID];
    const int tid = threadIdx.x;
#pragma unroll
    for (int it = 0; it < 16; ++it) {
        int idx = tid + 256 * it;
        Bs[idx >> 5][idx & 31] = B[idx];
    }
    int rowBase = blockIdx.x * 64;
    const unsigned* A2 = (const unsigned*)A;
#pragma unroll
    for (int it = 0; it < 16; ++it) {
        int idx = tid + 256 * it;
        int r = idx >> 6, c2 = idx & 63;
        int gr = rowBase + r;
        unsigned u = (gr < M) ? A2[(size_t)gr * 64 + c2] : 0u;
        As[r][2 * c2]     = lo16(u);
        As[r][2 * c2 + 1] = hi16(u);
    }
    __syncthreads();
    int col = tid & 31;
    int rg = tid >> 5;
    float acc[8];
#pragma unroll
    for (int i = 0; i < 8; ++i) acc[i] = 0.f;
    for (int k = 0; k < HID; ++k) {
        float b = Bs[k][col];
#pragma unroll
        for (int i = 0; i < 8; ++i) acc[i] += As[rg * 8 + i][k] * b;
    }
#pragma unroll
    for (int i = 0; i < 8; ++i) {
        int gr = rowBase + rg * 8 + i;
        if (gr < M) C[(size_t)gr * NCLS + col] = f2bf(acc[i] * dinv[gr]);
    }
}

// ---------------- agg2: quarter-wave per edge (4/wave), unroll x2 = 8 in flight ----------------
__global__ __launch_bounds__(256) void k_agg2(const unsigned short* __restrict__ h2s,
                                              const int* __restrict__ csr,
                                              const int* __restrict__ rs, const int* __restrict__ cnt,
                                              const float* __restrict__ dinv, const float* __restrict__ b2,
                                              float* __restrict__ out, int N) {
    int v = blockIdx.x * 4 + (threadIdx.x >> 6);
    if (v >= N) return;
    int lane = threadIdx.x & 63;
    int q = lane >> 4;
    int l = lane & 15;
    float dv = dinv[v];
    const unsigned* rows = (const unsigned*)h2s;   // 16 uints per row
    float ax = 0.f, ay = 0.f;
    if (q == 0) {
        unsigned u = rows[(size_t)v * 16 + l];   // self (pre-scaled)
        ax = lo16(u); ay = hi16(u);
    }
    int start = rs[v];
    int c = cnt[v];
    int i = q;
    for (; i + 4 < c; i += 8) {
        int s0 = csr[start + i];
        int s1 = csr[start + i + 4];
        unsigned u0 = rows[(size_t)s0 * 16 + l];
        unsigned u1 = rows[(size_t)s1 * 16 + l];
        ax += lo16(u0) + lo16(u1);
        ay += hi16(u0) + hi16(u1);
    }
    for (; i < c; i += 4) {
        int s = csr[start + i];
        unsigned u = rows[(size_t)s * 16 + l];
        ax += lo16(u);
        ay += hi16(u);
    }
    ax += __shfl_xor(ax, 16, 64);
    ax += __shfl_xor(ax, 32, 64);
    ay += __shfl_xor(ay, 16, 64);
    ay += __shfl_xor(ay, 32, 64);
    if (q == 0) {
        float2 bb = ((const float2*)b2)[l];
        float2 o;
        o.x = dv * ax + bb.x;
        o.y = dv * ay + bb.y;
        *((float2*)(out + (size_t)v * NCLS) + l) = o;
    }
}

// ---------------------------------------------------------------------------
extern "C" void kernel_launch(void* const* d_in, const int* in_sizes, int n_in,
                              void* d_out, int out_size, void* d_ws, size_t ws_size,
                              hipStream_t stream) {
    const float* x = (const float*)d_in[0];
    const int* edge_index = (const int*)d_in[1];
    const float* W1 = (const float*)d_in[2];
    const float* b1 = (const float*)d_in[3];
    const float* W2 = (const float*)d_in[4];
    const float* b2 = (const float*)d_in[5];
    float* out = (float*)d_out;

    const int N = in_sizes[0] / IN_F;       // 100000
    const int E = in_sizes[1] / 2;          // 1600000
    const int NB = (N + 63) >> 6;           // 1563 buckets
    const int* e_src = edge_index;
    const int* e_dst = edge_index + E;

    char* ws = (char*)d_ws;
    size_t off = 0;
    auto alloc = [&](size_t bytes) -> char* {
        char* p = ws + off;
        off += (bytes + 255) & ~(size_t)255;
        return p;
    };
    int* deg             = (int*)alloc((size_t)N * 4);
    float* dinv          = (float*)alloc((size_t)N * 4);
    int* rs              = (int*)alloc((size_t)N * 4);
    int* bcnt            = (int*)alloc(4096 * 4);
    int* boff            = (int*)alloc(4096 * 4);
    int* bcur            = (int*)alloc(4096 * 4);
    unsigned* stage      = (unsigned*)alloc((size_t)E * 4);
    int* csr             = (int*)alloc((size_t)E * 4);
    unsigned short* W1T  = (unsigned short*)alloc((size_t)HID * IN_F * 2);
    unsigned short* hs   = (unsigned short*)alloc((size_t)N * HID * 2);
    unsigned short* h1   = (unsigned short*)alloc((size_t)N * HID * 2);
    unsigned short* h2s  = (unsigned short*)alloc((size_t)N * NCLS * 2);

    const int nbE = (E + 255) / 256;
    const int nbN = (N + 255) / 256;
    const int nbNode = (N + 3) / 4;

    hipMemsetAsync(deg, 0, (size_t)N * 4, stream);
    k_hist<<<nbE, 256, 0, stream>>>(e_dst, deg, E);
    k_dinv<<<nbN, 256, 0, stream>>>(deg, dinv, bcnt, N);
    k_bscan<<<1, 256, 0, stream>>>(bcnt, boff, bcur, NB);
    k_bscatter<<<nbE, 256, 0, stream>>>(e_src, e_dst, bcur, stage, E);
    k_compact<<<NB, 256, 0, stream>>>(stage, boff, deg, rs, csr, N);
    k_prep<<<(HID * IN_F) / 256, 256, 0, stream>>>(W1, W1T);

    k_gemm1<<<(N + 63) / 64, 256, 0, stream>>>(x, W1T, dinv, hs, N);
    k_agg1<<<nbNode, 256, 0, stream>>>(hs, csr, rs, deg, dinv, b1, h1, N);
    k_gemm2<<<(N + 63) / 64, 256, 0, stream>>>(h1, W2, dinv, h2s, N);
    k_agg2<<<nbNode, 256, 0, stream>>>(h2s, csr, rs, deg, dinv, b2, out, N);
}

// Round 6
// 613.266 us; speedup vs baseline: 3.4728x; 1.2709x over previous
//
#include <hip/hip_runtime.h>
#include <hip/hip_bf16.h>
#include <cstddef>

// ---------------------------------------------------------------------------
// 2-layer GCN: out = A_norm(relu(A_norm(x@W1)+b1) @ W2) + b2
// R6: CSR scatter (R3 per-node-cursor form) fused into the GEMM1 kernel as a
// partitioned grid -> latency-bound scatter overlaps MFMA compute. agg1
// unroll x16; agg2 redesigned as 16-lane-per-node gather (1 line/edge).
// h/h1/h2 bf16, pre-scaled by dinv in GEMM epilogues.
// ---------------------------------------------------------------------------

#define IN_F 512
#define HID 128
#define NCLS 32

typedef __attribute__((ext_vector_type(8))) short bf16x8;
typedef __attribute__((ext_vector_type(4))) float f32x4;

__device__ __forceinline__ unsigned short f2bf(float f) {
    union { float f; unsigned u; } v; v.f = f;
    unsigned r = v.u + 0x7fff + ((v.u >> 16) & 1);   // RNE
    return (unsigned short)(r >> 16);
}
__device__ __forceinline__ float bf2f(unsigned short h) {
    union { unsigned u; float f; } v; v.u = ((unsigned)h) << 16;
    return v.f;
}
__device__ __forceinline__ float lo16(unsigned u) { return bf2f((unsigned short)(u & 0xffff)); }
__device__ __forceinline__ float hi16(unsigned u) { return bf2f((unsigned short)(u >> 16)); }

// ---------------- hist (edge histogram) fused with W1 transpose/cast ----------------
__global__ void k_histprep(const int* __restrict__ dst, int* __restrict__ deg, int E,
                           const float* __restrict__ W1, unsigned short* __restrict__ W1T, int PB) {
    int b = blockIdx.x;
    if (b < PB) {   // prep: 65536 elements over 256 blocks
        int i = b * 256 + threadIdx.x;
        int n = i >> 9, k = i & 511;
        W1T[(size_t)n * IN_F + k] = f2bf(W1[(size_t)k * HID + n]);
    } else {
        int e = (b - PB) * 256 + threadIdx.x;
        if (e < E) atomicAdd(&deg[dst[e]], 1);
    }
}

// ---------------- dinv = rsqrt(deg+1) ----------------
__global__ void k_dinv(const int* __restrict__ deg, float* __restrict__ dinv, int n) {
    int i = blockIdx.x * 256 + threadIdx.x;
    if (i < n) dinv[i] = rsqrtf((float)deg[i] + 1.0f);
}

// ---------------- 2-level exclusive scan (2048/block) ----------------
__global__ __launch_bounds__(256) void k_scan1(const int* __restrict__ deg, int* __restrict__ rs,
                                               int* __restrict__ bsum, int n) {
    __shared__ int sd[256];
    int base = blockIdx.x * 2048 + threadIdx.x * 8;
    int v[8];
    int t = 0;
#pragma unroll
    for (int i = 0; i < 8; ++i) {
        int x = (base + i < n) ? deg[base + i] : 0;
        v[i] = t;
        t += x;
    }
    sd[threadIdx.x] = t;
    __syncthreads();
    for (int off = 1; off < 256; off <<= 1) {
        int x = 0;
        if ((int)threadIdx.x >= off) x = sd[threadIdx.x - off];
        __syncthreads();
        if ((int)threadIdx.x >= off) sd[threadIdx.x] += x;
        __syncthreads();
    }
    int texcl = sd[threadIdx.x] - t;
#pragma unroll
    for (int i = 0; i < 8; ++i)
        if (base + i < n) rs[base + i] = texcl + v[i];
    if (threadIdx.x == 255) bsum[blockIdx.x] = sd[255];
}

__global__ void k_scan2(int* bsum, int nb) {
    if (threadIdx.x == 0 && blockIdx.x == 0) {
        int run = 0;
        for (int b = 0; b < nb; ++b) { int t = bsum[b]; bsum[b] = run; run += t; }
    }
}

__global__ void k_scan3(int* __restrict__ rs, const int* __restrict__ bsum,
                        int* __restrict__ cursor, int n) {
    int i = blockIdx.x * 256 + threadIdx.x;
    if (i < n) {
        int r = rs[i] + bsum[i >> 11];
        rs[i] = r;
        cursor[i] = r;
    }
}

// ---------------- FUSED: CSR scatter (blocks [0,NBS)) + GEMM1 (blocks [NBS,NBS+G)) ----------
// Scatter is memory-latency-bound, GEMM is MFMA/LDS-bound; co-resident waves overlap.
#define LSTR 40
#define SCHUNK 1024
__global__ __launch_bounds__(256) void k_fused(const float* __restrict__ A,
                                               const unsigned short* __restrict__ BT,
                                               const float* __restrict__ dinv,
                                               unsigned short* __restrict__ C, int M,
                                               const int* __restrict__ src, const int* __restrict__ dst,
                                               int* cursor, int* __restrict__ csr, int E, int NBS) {
    const int bid = blockIdx.x;
    const int tid = threadIdx.x;
    if (bid < NBS) {
        // ---- scatter phase: per-node cursors (R3 form) ----
        int base = bid * SCHUNK;
        int lim = base + SCHUNK;
        if (lim > E) lim = E;
        for (int e = base + tid; e < lim; e += 256) {
            int d = dst[e];
            int pos = atomicAdd(&cursor[d], 1);
            csr[pos] = src[e];
        }
        return;
    }
    // ---- GEMM phase ----
    __shared__ unsigned short As[64 * LSTR];
    __shared__ unsigned short Bs[128 * LSTR];
    const int wave = tid >> 6;
    const int lane = tid & 63;
    const int l16 = lane & 15;
    const int q = lane >> 4;
    const int rowBase = (bid - NBS) * 64;

    const int ar = tid >> 2, akc = tid & 3;
    const int agr = rowBase + ar;
    const int bn0 = tid >> 2, bn1 = 64 + (tid >> 2), bkc = tid & 3;

    f32x4 acc[8];
#pragma unroll
    for (int nt = 0; nt < 8; ++nt) acc[nt] = (f32x4){0.f, 0.f, 0.f, 0.f};

    float4 pa0, pa1;
    uint4 pb0, pb1;
    auto load_tile = [&](int k0, float4& a0, float4& a1, uint4& b0, uint4& b1) {
        if (agr < M) {
            const float* ap = A + (size_t)agr * IN_F + k0 + akc * 8;
            a0 = *(const float4*)ap;
            a1 = *(const float4*)(ap + 4);
        } else {
            a0 = make_float4(0.f, 0.f, 0.f, 0.f);
            a1 = a0;
        }
        b0 = *(const uint4*)(BT + (size_t)bn0 * IN_F + k0 + bkc * 8);
        b1 = *(const uint4*)(BT + (size_t)bn1 * IN_F + k0 + bkc * 8);
    };

    load_tile(0, pa0, pa1, pb0, pb1);

    for (int t = 0; t < 16; ++t) {
        ushort4 lohalf, hihalf;
        lohalf.x = f2bf(pa0.x); lohalf.y = f2bf(pa0.y); lohalf.z = f2bf(pa0.z); lohalf.w = f2bf(pa0.w);
        hihalf.x = f2bf(pa1.x); hihalf.y = f2bf(pa1.y); hihalf.z = f2bf(pa1.z); hihalf.w = f2bf(pa1.w);
        *(ushort4*)(As + ar * LSTR + akc * 8) = lohalf;
        *(ushort4*)(As + ar * LSTR + akc * 8 + 4) = hihalf;
        *(uint4*)(Bs + bn0 * LSTR + bkc * 8) = pb0;
        *(uint4*)(Bs + bn1 * LSTR + bkc * 8) = pb1;
        __syncthreads();

        float4 na0, na1;
        uint4 nb0, nb1;
        if (t < 15) load_tile((t + 1) * 32, na0, na1, nb0, nb1);

        bf16x8 a_frag = *(const bf16x8*)(As + (wave * 16 + l16) * LSTR + q * 8);
        bf16x8 b_frag[8];
#pragma unroll
        for (int nt = 0; nt < 8; ++nt)
            b_frag[nt] = *(const bf16x8*)(Bs + (nt * 16 + l16) * LSTR + q * 8);
#pragma unroll
        for (int nt = 0; nt < 8; ++nt)
            acc[nt] = __builtin_amdgcn_mfma_f32_16x16x32_bf16(a_frag, b_frag[nt], acc[nt], 0, 0, 0);
        __syncthreads();
        pa0 = na0; pa1 = na1; pb0 = nb0; pb1 = nb1;
    }

#pragma unroll
    for (int r = 0; r < 4; ++r) {
        int row = rowBase + wave * 16 + q * 4 + r;
        if (row < M) {
            float sc = dinv[row];
#pragma unroll
            for (int nt = 0; nt < 8; ++nt)
                C[(size_t)row * HID + nt * 16 + l16] = f2bf(acc[nt][r] * sc);
        }
    }
}

// ---------------- agg1: one wave per node, unroll x16 ----------------
__global__ __launch_bounds__(256) void k_agg1(const unsigned short* __restrict__ hs,
                                              const int* __restrict__ csr,
                                              const int* __restrict__ rs, const int* __restrict__ cnt,
                                              const float* __restrict__ dinv, const float* __restrict__ b1,
                                              unsigned short* __restrict__ h1, int N) {
    int v = blockIdx.x * 4 + (threadIdx.x >> 6);
    if (v >= N) return;
    int lane = threadIdx.x & 63;
    float dv = dinv[v];
    const unsigned* hrow = (const unsigned*)hs;
    unsigned u = hrow[(size_t)v * 64 + lane];   // self (pre-scaled)
    float ax = lo16(u), ay = hi16(u);
    int start = rs[v];
    int c = cnt[v];
    int i = 0;
    for (; i + 16 <= c; i += 16) {
        int s[16];
        unsigned uu[16];
#pragma unroll
        for (int j = 0; j < 16; ++j) s[j] = csr[start + i + j];
#pragma unroll
        for (int j = 0; j < 16; ++j) uu[j] = hrow[(size_t)s[j] * 64 + lane];
#pragma unroll
        for (int j = 0; j < 16; ++j) { ax += lo16(uu[j]); ay += hi16(uu[j]); }
    }
    for (; i + 4 <= c; i += 4) {
        int s[4];
        unsigned uu[4];
#pragma unroll
        for (int j = 0; j < 4; ++j) s[j] = csr[start + i + j];
#pragma unroll
        for (int j = 0; j < 4; ++j) uu[j] = hrow[(size_t)s[j] * 64 + lane];
#pragma unroll
        for (int j = 0; j < 4; ++j) { ax += lo16(uu[j]); ay += hi16(uu[j]); }
    }
    for (; i < c; ++i) {
        int s = csr[start + i];
        unsigned us = hrow[(size_t)s * 64 + lane];
        ax += lo16(us);
        ay += hi16(us);
    }
    float2 bb = ((const float2*)b1)[lane];
    float ox = fmaxf(dv * ax + bb.x, 0.f);
    float oy = fmaxf(dv * ay + bb.y, 0.f);
    ((unsigned*)h1)[(size_t)v * 64 + lane] =
        (unsigned)f2bf(ox) | ((unsigned)f2bf(oy) << 16);
}

// ---------------- GEMM2: h1[M,128]bf16 @ W2[128,32]fp32 -> h2s[M,32]bf16 (dinv-scaled) ----------------
__global__ __launch_bounds__(256) void k_gemm2(const unsigned short* __restrict__ A,
                                               const float* __restrict__ B,
                                               const float* __restrict__ dinv,
                                               unsigned short* __restrict__ C, int M) {
    __shared__ float Bs[HID][NCLS];
    __shared__ float As[64][HID];
    const int tid = threadIdx.x;
#pragma unroll
    for (int it = 0; it < 16; ++it) {
        int idx = tid + 256 * it;
        Bs[idx >> 5][idx & 31] = B[idx];
    }
    int rowBase = blockIdx.x * 64;
    const unsigned* A2 = (const unsigned*)A;
#pragma unroll
    for (int it = 0; it < 16; ++it) {
        int idx = tid + 256 * it;
        int r = idx >> 6, c2 = idx & 63;
        int gr = rowBase + r;
        unsigned u = (gr < M) ? A2[(size_t)gr * 64 + c2] : 0u;
        As[r][2 * c2]     = lo16(u);
        As[r][2 * c2 + 1] = hi16(u);
    }
    __syncthreads();
    int col = tid & 31;
    int rg = tid >> 5;
    float acc[8];
#pragma unroll
    for (int i = 0; i < 8; ++i) acc[i] = 0.f;
    for (int k = 0; k < HID; ++k) {
        float b = Bs[k][col];
#pragma unroll
        for (int i = 0; i < 8; ++i) acc[i] += As[rg * 8 + i][k] * b;
    }
#pragma unroll
    for (int i = 0; i < 8; ++i) {
        int gr = rowBase + rg * 8 + i;
        if (gr < M) C[(size_t)gr * NCLS + col] = f2bf(acc[i] * dinv[gr]);
    }
}

// ---------------- agg2: 16 lanes per node (row = 1 cache line), unroll x8 ----------------
__global__ __launch_bounds__(256) void k_agg2(const unsigned short* __restrict__ h2s,
                                              const int* __restrict__ csr,
                                              const int* __restrict__ rs, const int* __restrict__ cnt,
                                              const float* __restrict__ dinv, const float* __restrict__ b2,
                                              float* __restrict__ out, int N) {
    int g = threadIdx.x >> 4;       // node slot 0..15
    int l = threadIdx.x & 15;       // 2 feats per lane
    int v = blockIdx.x * 16 + g;
    if (v >= N) return;
    float dv = dinv[v];
    const unsigned* rows = (const unsigned*)h2s;   // 16 uints per row
    unsigned u = rows[(size_t)v * 16 + l];         // self (pre-scaled)
    float ax = lo16(u), ay = hi16(u);
    int start = rs[v];
    int c = cnt[v];
    int i = 0;
    for (; i + 8 <= c; i += 8) {
        int s[8];
        unsigned uu[8];
#pragma unroll
        for (int j = 0; j < 8; ++j) s[j] = csr[start + i + j];
#pragma unroll
        for (int j = 0; j < 8; ++j) uu[j] = rows[(size_t)s[j] * 16 + l];
#pragma unroll
        for (int j = 0; j < 8; ++j) { ax += lo16(uu[j]); ay += hi16(uu[j]); }
    }
    for (; i < c; ++i) {
        int s = csr[start + i];
        unsigned us = rows[(size_t)s * 16 + l];
        ax += lo16(us);
        ay += hi16(us);
    }
    float2 bb = ((const float2*)b2)[l];
    float2 o;
    o.x = dv * ax + bb.x;
    o.y = dv * ay + bb.y;
    *((float2*)(out + (size_t)v * NCLS) + l) = o;
}

// ---------------------------------------------------------------------------
extern "C" void kernel_launch(void* const* d_in, const int* in_sizes, int n_in,
                              void* d_out, int out_size, void* d_ws, size_t ws_size,
                              hipStream_t stream) {
    const float* x = (const float*)d_in[0];
    const int* edge_index = (const int*)d_in[1];
    const float* W1 = (const float*)d_in[2];
    const float* b1 = (const float*)d_in[3];
    const float* W2 = (const float*)d_in[4];
    const float* b2 = (const float*)d_in[5];
    float* out = (float*)d_out;

    const int N = in_sizes[0] / IN_F;       // 100000
    const int E = in_sizes[1] / 2;          // 1600000
    const int* e_src = edge_index;
    const int* e_dst = edge_index + E;

    char* ws = (char*)d_ws;
    size_t off = 0;
    auto alloc = [&](size_t bytes) -> char* {
        char* p = ws + off;
        off += (bytes + 255) & ~(size_t)255;
        return p;
    };
    int* deg             = (int*)alloc((size_t)N * 4);
    float* dinv          = (float*)alloc((size_t)N * 4);
    int* rs              = (int*)alloc((size_t)N * 4);
    int* cursor          = (int*)alloc((size_t)N * 4);
    int* bsum            = (int*)alloc(1024 * 4);
    int* csr             = (int*)alloc((size_t)E * 4);
    unsigned short* W1T  = (unsigned short*)alloc((size_t)HID * IN_F * 2);
    unsigned short* hs   = (unsigned short*)alloc((size_t)N * HID * 2);
    unsigned short* h1   = (unsigned short*)alloc((size_t)N * HID * 2);
    unsigned short* h2s  = (unsigned short*)alloc((size_t)N * NCLS * 2);

    const int nbE = (E + 255) / 256;
    const int nbN = (N + 255) / 256;
    const int nbScan = (N + 2047) / 2048;
    const int PB = (HID * IN_F) / 256;          // 256 prep blocks
    const int NBS = (E + SCHUNK - 1) / SCHUNK;  // 1563 scatter blocks
    const int NBG = (N + 63) / 64;              // 1563 gemm blocks

    hipMemsetAsync(deg, 0, (size_t)N * 4, stream);
    k_histprep<<<PB + nbE, 256, 0, stream>>>(e_dst, deg, E, W1, W1T, PB);
    k_dinv<<<nbN, 256, 0, stream>>>(deg, dinv, N);
    k_scan1<<<nbScan, 256, 0, stream>>>(deg, rs, bsum, N);
    k_scan2<<<1, 64, 0, stream>>>(bsum, nbScan);
    k_scan3<<<nbN, 256, 0, stream>>>(rs, bsum, cursor, N);

    k_fused<<<NBS + NBG, 256, 0, stream>>>(x, W1T, dinv, hs, N, e_src, e_dst, cursor, csr, E, NBS);

    k_agg1<<<(N + 3) / 4, 256, 0, stream>>>(hs, csr, rs, deg, dinv, b1, h1, N);
    k_gemm2<<<(N + 63) / 64, 256, 0, stream>>>(h1, W2, dinv, h2s, N);
    k_agg2<<<(N + 15) / 16, 256, 0, stream>>>(h2s, csr, rs, deg, dinv, b2, out, N);
}

// Round 7
// 550.079 us; speedup vs baseline: 3.8717x; 1.1149x over previous
//
#include <hip/hip_runtime.h>
#include <hip/hip_bf16.h>
#include <cstddef>

// ---------------------------------------------------------------------------
// 2-layer GCN: out = A_norm(relu(A_norm(x@W1)+b1) @ W2) + b2
// R7: (1) k_fused interleaves scatter/gemm blocks (bid&1) for true overlap;
// (2) scatter de-atomized: hist stores per-edge rank (atomicAdd return),
// scatter = pure store csr[rs[dst]+rank]=src, unroll x4; (3) CSR spans padded
// to x8 with dummy zero-row -> branchless constant-MLP agg loops.
// h/h1/h2 bf16, pre-scaled by dinv in GEMM epilogues.
// ---------------------------------------------------------------------------

#define IN_F 512
#define HID 128
#define NCLS 32

typedef __attribute__((ext_vector_type(8))) short bf16x8;
typedef __attribute__((ext_vector_type(4))) float f32x4;

__device__ __forceinline__ unsigned short f2bf(float f) {
    union { float f; unsigned u; } v; v.f = f;
    unsigned r = v.u + 0x7fff + ((v.u >> 16) & 1);   // RNE
    return (unsigned short)(r >> 16);
}
__device__ __forceinline__ float bf2f(unsigned short h) {
    union { unsigned u; float f; } v; v.u = ((unsigned)h) << 16;
    return v.f;
}
__device__ __forceinline__ float lo16(unsigned u) { return bf2f((unsigned short)(u & 0xffff)); }
__device__ __forceinline__ float hi16(unsigned u) { return bf2f((unsigned short)(u >> 16)); }

// ---------------- hist (stores per-edge rank) fused with W1 transpose/cast ----------------
__global__ void k_histprep(const int* __restrict__ dst, int* __restrict__ deg,
                           int* __restrict__ rank, int E,
                           const float* __restrict__ W1, unsigned short* __restrict__ W1T, int PB) {
    int b = blockIdx.x;
    if (b < PB) {   // prep: 65536 elements over 256 blocks
        int i = b * 256 + threadIdx.x;
        int n = i >> 9, k = i & 511;
        W1T[(size_t)n * IN_F + k] = f2bf(W1[(size_t)k * HID + n]);
    } else {
        int e = (b - PB) * 256 + threadIdx.x;
        if (e < E) rank[e] = atomicAdd(&deg[dst[e]], 1);
    }
}

// ---------------- dinv = rsqrt(deg+1); also zero the dummy rows ----------------
__global__ void k_dinv(const int* __restrict__ deg, float* __restrict__ dinv, int n,
                       unsigned* __restrict__ hsu, unsigned* __restrict__ h2su) {
    int i = blockIdx.x * 256 + threadIdx.x;
    if (i < n) dinv[i] = rsqrtf((float)deg[i] + 1.0f);
    if (blockIdx.x == 0) {
        if (threadIdx.x < 64) hsu[(size_t)n * 64 + threadIdx.x] = 0u;   // hs row N = 0
        if (threadIdx.x < 16) h2su[(size_t)n * 16 + threadIdx.x] = 0u;  // h2s row N = 0
    }
}

// ---------------- 2-level exclusive scan over PADDED counts ((deg+7)&~7) ----------------
__global__ __launch_bounds__(256) void k_scan1(const int* __restrict__ deg, int* __restrict__ rs,
                                               int* __restrict__ bsum, int n) {
    __shared__ int sd[256];
    int base = blockIdx.x * 2048 + threadIdx.x * 8;
    int v[8];
    int t = 0;
#pragma unroll
    for (int i = 0; i < 8; ++i) {
        int x = (base + i < n) ? ((deg[base + i] + 7) & ~7) : 0;
        v[i] = t;
        t += x;
    }
    sd[threadIdx.x] = t;
    __syncthreads();
    for (int off = 1; off < 256; off <<= 1) {
        int x = 0;
        if ((int)threadIdx.x >= off) x = sd[threadIdx.x - off];
        __syncthreads();
        if ((int)threadIdx.x >= off) sd[threadIdx.x] += x;
        __syncthreads();
    }
    int texcl = sd[threadIdx.x] - t;
#pragma unroll
    for (int i = 0; i < 8; ++i)
        if (base + i < n) rs[base + i] = texcl + v[i];
    if (threadIdx.x == 255) bsum[blockIdx.x] = sd[255];
}

__global__ void k_scan2(int* bsum, int nb) {
    if (threadIdx.x == 0 && blockIdx.x == 0) {
        int run = 0;
        for (int b = 0; b < nb; ++b) { int t = bsum[b]; bsum[b] = run; run += t; }
    }
}

// finalize rs and fill pad slots of csr with dummy index n (zero row)
__global__ void k_scan3(int* __restrict__ rs, const int* __restrict__ bsum,
                        const int* __restrict__ deg, int* __restrict__ csr, int n) {
    int i = blockIdx.x * 256 + threadIdx.x;
    if (i < n) {
        int r = rs[i] + bsum[i >> 11];
        rs[i] = r;
        int d = deg[i];
        int pc = (d + 7) & ~7;
        for (int j = d; j < pc; ++j) csr[r + j] = n;
    }
}

// ---------------- FUSED: GEMM1 (even blocks) + atomic-free scatter (odd blocks) ----------
#define LSTR 40
#define SCHUNK 1024
__global__ __launch_bounds__(256) void k_fused(const float* __restrict__ A,
                                               const unsigned short* __restrict__ BT,
                                               const float* __restrict__ dinv,
                                               unsigned short* __restrict__ C, int M,
                                               const int* __restrict__ src, const int* __restrict__ dst,
                                               const int* __restrict__ rank, const int* __restrict__ rs,
                                               int* __restrict__ csr, int E) {
    const int bid = blockIdx.x;
    const int tid = threadIdx.x;
    if (bid & 1) {
        // ---- scatter: csr[rs[dst]+rank] = src, no atomics, 4 chains in flight ----
        int base = (bid >> 1) * SCHUNK + tid;
        int d[4], s[4], rk[4];
        bool val[4];
#pragma unroll
        for (int j = 0; j < 4; ++j) {
            int e = base + j * 256;
            val[j] = e < E;
            if (val[j]) { d[j] = dst[e]; s[j] = src[e]; rk[j] = rank[e]; }
        }
#pragma unroll
        for (int j = 0; j < 4; ++j)
            if (val[j]) csr[rs[d[j]] + rk[j]] = s[j];
        return;
    }
    // ---- GEMM phase ----
    __shared__ unsigned short As[64 * LSTR];
    __shared__ unsigned short Bs[128 * LSTR];
    const int wave = tid >> 6;
    const int lane = tid & 63;
    const int l16 = lane & 15;
    const int q = lane >> 4;
    const int rowBase = (bid >> 1) * 64;

    const int ar = tid >> 2, akc = tid & 3;
    const int agr = rowBase + ar;
    const int bn0 = tid >> 2, bn1 = 64 + (tid >> 2), bkc = tid & 3;

    f32x4 acc[8];
#pragma unroll
    for (int nt = 0; nt < 8; ++nt) acc[nt] = (f32x4){0.f, 0.f, 0.f, 0.f};

    float4 pa0, pa1;
    uint4 pb0, pb1;
    auto load_tile = [&](int k0, float4& a0, float4& a1, uint4& b0, uint4& b1) {
        if (agr < M) {
            const float* ap = A + (size_t)agr * IN_F + k0 + akc * 8;
            a0 = *(const float4*)ap;
            a1 = *(const float4*)(ap + 4);
        } else {
            a0 = make_float4(0.f, 0.f, 0.f, 0.f);
            a1 = a0;
        }
        b0 = *(const uint4*)(BT + (size_t)bn0 * IN_F + k0 + bkc * 8);
        b1 = *(const uint4*)(BT + (size_t)bn1 * IN_F + k0 + bkc * 8);
    };

    load_tile(0, pa0, pa1, pb0, pb1);

    for (int t = 0; t < 16; ++t) {
        ushort4 lohalf, hihalf;
        lohalf.x = f2bf(pa0.x); lohalf.y = f2bf(pa0.y); lohalf.z = f2bf(pa0.z); lohalf.w = f2bf(pa0.w);
        hihalf.x = f2bf(pa1.x); hihalf.y = f2bf(pa1.y); hihalf.z = f2bf(pa1.z); hihalf.w = f2bf(pa1.w);
        *(ushort4*)(As + ar * LSTR + akc * 8) = lohalf;
        *(ushort4*)(As + ar * LSTR + akc * 8 + 4) = hihalf;
        *(uint4*)(Bs + bn0 * LSTR + bkc * 8) = pb0;
        *(uint4*)(Bs + bn1 * LSTR + bkc * 8) = pb1;
        __syncthreads();

        float4 na0, na1;
        uint4 nb0, nb1;
        if (t < 15) load_tile((t + 1) * 32, na0, na1, nb0, nb1);

        bf16x8 a_frag = *(const bf16x8*)(As + (wave * 16 + l16) * LSTR + q * 8);
        bf16x8 b_frag[8];
#pragma unroll
        for (int nt = 0; nt < 8; ++nt)
            b_frag[nt] = *(const bf16x8*)(Bs + (nt * 16 + l16) * LSTR + q * 8);
#pragma unroll
        for (int nt = 0; nt < 8; ++nt)
            acc[nt] = __builtin_amdgcn_mfma_f32_16x16x32_bf16(a_frag, b_frag[nt], acc[nt], 0, 0, 0);
        __syncthreads();
        pa0 = na0; pa1 = na1; pb0 = nb0; pb1 = nb1;
    }

#pragma unroll
    for (int r = 0; r < 4; ++r) {
        int row = rowBase + wave * 16 + q * 4 + r;
        if (row < M) {
            float sc = dinv[row];
#pragma unroll
            for (int nt = 0; nt < 8; ++nt)
                C[(size_t)row * HID + nt * 16 + l16] = f2bf(acc[nt][r] * sc);
        }
    }
}

// ---------------- agg1: one wave per node, branchless padded x8 ----------------
__global__ __launch_bounds__(256) void k_agg1(const unsigned short* __restrict__ hs,
                                              const int* __restrict__ csr,
                                              const int* __restrict__ rs, const int* __restrict__ cnt,
                                              const float* __restrict__ dinv, const float* __restrict__ b1,
                                              unsigned short* __restrict__ h1, int N) {
    int v = blockIdx.x * 4 + (threadIdx.x >> 6);
    if (v >= N) return;
    int lane = threadIdx.x & 63;
    float dv = dinv[v];
    const unsigned* hrow = (const unsigned*)hs;
    unsigned u = hrow[(size_t)v * 64 + lane];   // self (pre-scaled)
    float ax = lo16(u), ay = hi16(u);
    int start = rs[v];
    int pc = (cnt[v] + 7) & ~7;
    for (int i = 0; i < pc; i += 8) {
        int s[8];
        unsigned uu[8];
#pragma unroll
        for (int j = 0; j < 8; ++j) s[j] = csr[start + i + j];
#pragma unroll
        for (int j = 0; j < 8; ++j) uu[j] = hrow[(size_t)s[j] * 64 + lane];
#pragma unroll
        for (int j = 0; j < 8; ++j) { ax += lo16(uu[j]); ay += hi16(uu[j]); }
    }
    float2 bb = ((const float2*)b1)[lane];
    float ox = fmaxf(dv * ax + bb.x, 0.f);
    float oy = fmaxf(dv * ay + bb.y, 0.f);
    ((unsigned*)h1)[(size_t)v * 64 + lane] =
        (unsigned)f2bf(ox) | ((unsigned)f2bf(oy) << 16);
}

// ---------------- GEMM2: h1[M,128]bf16 @ W2[128,32]fp32 -> h2s[M,32]bf16 (dinv-scaled) ----------------
__global__ __launch_bounds__(256) void k_gemm2(const unsigned short* __restrict__ A,
                                               const float* __restrict__ B,
                                               const float* __restrict__ dinv,
                                               unsigned short* __restrict__ C, int M) {
    __shared__ float Bs[HID][NCLS];
    __shared__ float As[64][HID];
    const int tid = threadIdx.x;
#pragma unroll
    for (int it = 0; it < 16; ++it) {
        int idx = tid + 256 * it;
        Bs[idx >> 5][idx & 31] = B[idx];
    }
    int rowBase = blockIdx.x * 64;
    const unsigned* A2 = (const unsigned*)A;
#pragma unroll
    for (int it = 0; it < 16; ++it) {
        int idx = tid + 256 * it;
        int r = idx >> 6, c2 = idx & 63;
        int gr = rowBase + r;
        unsigned u = (gr < M) ? A2[(size_t)gr * 64 + c2] : 0u;
        As[r][2 * c2]     = lo16(u);
        As[r][2 * c2 + 1] = hi16(u);
    }
    __syncthreads();
    int col = tid & 31;
    int rg = tid >> 5;
    float acc[8];
#pragma unroll
    for (int i = 0; i < 8; ++i) acc[i] = 0.f;
    for (int k = 0; k < HID; ++k) {
        float b = Bs[k][col];
#pragma unroll
        for (int i = 0; i < 8; ++i) acc[i] += As[rg * 8 + i][k] * b;
    }
#pragma unroll
    for (int i = 0; i < 8; ++i) {
        int gr = rowBase + rg * 8 + i;
        if (gr < M) C[(size_t)gr * NCLS + col] = f2bf(acc[i] * dinv[gr]);
    }
}

// ---------------- agg2: 16 lanes per node (row = 1 cache line), branchless padded x8 ----------------
__global__ __launch_bounds__(256) void k_agg2(const unsigned short* __restrict__ h2s,
                                              const int* __restrict__ csr,
                                              const int* __restrict__ rs, const int* __restrict__ cnt,
                                              const float* __restrict__ dinv, const float* __restrict__ b2,
                                              float* __restrict__ out, int N) {
    int g = threadIdx.x >> 4;       // node slot 0..15
    int l = threadIdx.x & 15;       // 2 feats per lane
    int v = blockIdx.x * 16 + g;
    if (v >= N) return;
    float dv = dinv[v];
    const unsigned* rows = (const unsigned*)h2s;   // 16 uints per row
    unsigned u = rows[(size_t)v * 16 + l];         // self (pre-scaled)
    float ax = lo16(u), ay = hi16(u);
    int start = rs[v];
    int pc = (cnt[v] + 7) & ~7;
    for (int i = 0; i < pc; i += 8) {
        int s[8];
        unsigned uu[8];
#pragma unroll
        for (int j = 0; j < 8; ++j) s[j] = csr[start + i + j];
#pragma unroll
        for (int j = 0; j < 8; ++j) uu[j] = rows[(size_t)s[j] * 16 + l];
#pragma unroll
        for (int j = 0; j < 8; ++j) { ax += lo16(uu[j]); ay += hi16(uu[j]); }
    }
    float2 bb = ((const float2*)b2)[l];
    float2 o;
    o.x = dv * ax + bb.x;
    o.y = dv * ay + bb.y;
    *((float2*)(out + (size_t)v * NCLS) + l) = o;
}

// ---------------------------------------------------------------------------
extern "C" void kernel_launch(void* const* d_in, const int* in_sizes, int n_in,
                              void* d_out, int out_size, void* d_ws, size_t ws_size,
                              hipStream_t stream) {
    const float* x = (const float*)d_in[0];
    const int* edge_index = (const int*)d_in[1];
    const float* W1 = (const float*)d_in[2];
    const float* b1 = (const float*)d_in[3];
    const float* W2 = (const float*)d_in[4];
    const float* b2 = (const float*)d_in[5];
    float* out = (float*)d_out;

    const int N = in_sizes[0] / IN_F;       // 100000
    const int E = in_sizes[1] / 2;          // 1600000
    const int* e_src = edge_index;
    const int* e_dst = edge_index + E;

    char* ws = (char*)d_ws;
    size_t off = 0;
    auto alloc = [&](size_t bytes) -> char* {
        char* p = ws + off;
        off += (bytes + 255) & ~(size_t)255;
        return p;
    };
    int* deg             = (int*)alloc((size_t)N * 4);
    float* dinv          = (float*)alloc((size_t)N * 4);
    int* rs              = (int*)alloc((size_t)N * 4);
    int* bsum            = (int*)alloc(1024 * 4);
    int* csr             = (int*)alloc(((size_t)E + 8 * (size_t)N) * 4);  // padded CSR
    unsigned short* W1T  = (unsigned short*)alloc((size_t)HID * IN_F * 2);
    unsigned short* hs   = (unsigned short*)alloc((size_t)(N + 1) * HID * 2);  // +1 dummy zero row
    unsigned short* h1   = (unsigned short*)alloc((size_t)N * HID * 2);
    unsigned short* h2s  = (unsigned short*)alloc((size_t)(N + 1) * NCLS * 2); // +1 dummy zero row
    int* rank            = (int*)h1;   // rank dead before agg1 writes h1

    const int nbE = (E + 255) / 256;
    const int nbN = (N + 255) / 256;
    const int nbScan = (N + 2047) / 2048;
    const int PB = (HID * IN_F) / 256;          // 256 prep blocks
    const int NBG = (N + 63) / 64;              // 1563 gemm tiles; scatter chunks = same count

    hipMemsetAsync(deg, 0, (size_t)N * 4, stream);
    k_histprep<<<PB + nbE, 256, 0, stream>>>(e_dst, deg, rank, E, W1, W1T, PB);
    k_dinv<<<nbN, 256, 0, stream>>>(deg, dinv, N, (unsigned*)hs, (unsigned*)h2s);
    k_scan1<<<nbScan, 256, 0, stream>>>(deg, rs, bsum, N);
    k_scan2<<<1, 64, 0, stream>>>(bsum, nbScan);
    k_scan3<<<nbN, 256, 0, stream>>>(rs, bsum, deg, csr, N);

    k_fused<<<2 * NBG, 256, 0, stream>>>(x, W1T, dinv, hs, N, e_src, e_dst, rank, rs, csr, E);

    k_agg1<<<(N + 3) / 4, 256, 0, stream>>>(hs, csr, rs, deg, dinv, b1, h1, N);
    k_gemm2<<<(N + 63) / 64, 256, 0, stream>>>(h1, W2, dinv, h2s, N);
    k_agg2<<<(N + 15) / 16, 256, 0, stream>>>(h2s, csr, rs, deg, dinv, b2, out, N);
}